// Round 18
// baseline (404.497 us; speedup 1.0000x reference)
//
#include <hip/hip_runtime.h>

typedef unsigned int u32;
typedef unsigned short ushort_t;
typedef __attribute__((ext_vector_type(8))) short bf16x8;
typedef __attribute__((ext_vector_type(4))) float f32x4;

#define PCAP 3072          // per-bucket fixed capacity (mean 2046, sigma ~45)
#define OVFCAP 1600000     // overflow list capacity = E (unconditional correctness)

__device__ __forceinline__ float bf2f_lo(u32 u){
  union{u32 i; float f;} v; v.i = u<<16; return v.f;
}
__device__ __forceinline__ float bf2f_hi(u32 u){
  union{u32 i; float f;} v; v.i = u & 0xFFFF0000u; return v.f;
}
__device__ __forceinline__ u32 pack2bf(float a, float b){
  union{float f; u32 i;} va, vb; va.f=a; vb.f=b;
  u32 ra = (va.i + 0x7FFF + ((va.i>>16)&1)) >> 16;          // RNE
  u32 rb = (vb.i + 0x7FFF + ((vb.i>>16)&1)) & 0xFFFF0000u;
  return ra | rb;
}
__device__ __forceinline__ ushort_t f2bf1(float f){
  union{float f; u32 i;} v; v.f=f;
  u32 r = v.i + 0x7FFF + ((v.i>>16)&1);
  return (ushort_t)(r>>16);
}

// =============== prep: x->bf16, W1^T, W2^T, zero control bufs (one launch) ===============
__global__ __launch_bounds__(256) void prep(const float* __restrict__ x, u32* __restrict__ xb, long nconv,
                                            const float* __restrict__ W1, ushort_t* __restrict__ W1t,
                                            const float* __restrict__ W2, ushort_t* __restrict__ W2t,
                                            int* __restrict__ bcursor, int* __restrict__ ovf_cnt, int NB){
  long blk = blockIdx.x;
  int tid = threadIdx.x;
  if(blk < nconv){
    long i = blk*256 + tid;
    float4 v = ((const float4*)x)[i];
    uint2 o; o.x = pack2bf(v.x, v.y); o.y = pack2bf(v.z, v.w);
    ((uint2*)xb)[i] = o;
  } else if(blk < nconv + 256){
    int n = (int)(blk - nconv);
    for(int k = tid; k < 128; k += 256) W1t[(size_t)n*128 + k] = f2bf1(W1[(size_t)k*256 + n]);
  } else if(blk < nconv + 512){
    int n = (int)(blk - nconv - 256);
    for(int k = tid; k < 256; k += 256) W2t[(size_t)n*256 + k] = f2bf1(W2[(size_t)k*256 + n]);
  } else {
    for(int i = tid; i < NB*16; i += 256) bcursor[i] = 0;
    if(tid == 0){ ovf_cnt[0] = 0; ovf_cnt[16] = 0; }   // [16] = tail done-counter
  }
}

// =============== direct binned scatter ===============
__global__ __launch_bounds__(256) void binscatter_direct(const int* __restrict__ src, const int* __restrict__ dst,
                                                         int* __restrict__ bcursor, u32* __restrict__ pairs,
                                                         int* __restrict__ ovf, int* __restrict__ ovf_cnt,
                                                         int E, int N, int NB){
  __shared__ int hist[1024];
  __shared__ int base[1024];
  int e0 = blockIdx.x*4096;
  int e1 = min(e0+4096, E);
  for(int i=threadIdx.x; i<NB; i+=256) hist[i]=0;
  __syncthreads();
  for(int i=e0+threadIdx.x; i<e1; i+=256){
    int d = dst[i];
    if((u32)d >= (u32)N) d = 0;
    atomicAdd(&hist[d>>6], 1);
  }
  __syncthreads();
  for(int i=threadIdx.x; i<NB; i+=256){
    int c = hist[i];
    base[i] = c ? atomicAdd(&bcursor[i*16], c) : 0;
    hist[i] = 0;
  }
  __syncthreads();
  for(int i=e0+threadIdx.x; i<e1; i+=256){
    int d = dst[i]; if((u32)d >= (u32)N) d = 0;
    int s = src[i]; if((u32)s >= (u32)N) s = 0;
    int b = d>>6;
    int loc = atomicAdd(&hist[b], 1);
    int pos = base[b] + loc;
    if(pos < PCAP){
      pairs[(size_t)b*PCAP + pos] = (u32)s | (((u32)(d & 63))<<17);
    } else {
      int o = atomicAdd(ovf_cnt, 1);
      if(o < OVFCAP){ ovf[2*o] = s; ovf[2*o+1] = d; }
    }
  }
}

// =============== fused bucket-CSR + gather: one block(512) per 64-node bucket ===============
__global__ __launch_bounds__(512) void gather_bucket(const u32* __restrict__ xb,
                                                     const u32* __restrict__ pairs,
                                                     const int* __restrict__ bcursor,
                                                     const int* __restrict__ ovf, const int* __restrict__ ovf_cnt,
                                                     u32* __restrict__ h0b, int N){
  __shared__ int lsrc[PCAP];
  __shared__ int dcnt[64];
  __shared__ int dstart[65];
  __shared__ int dcur[64];
  __shared__ int s_ovfn;
  int b = blockIdx.x;
  int tid = threadIdx.x;
  int cnt = bcursor[b*16];
  if(cnt < 0) cnt = 0;
  int cl = min(cnt, PCAP);
  if(tid < 64) dcnt[tid] = 0;
  if(tid == 0){ int o = *ovf_cnt; s_ovfn = (o < 0) ? 0 : min(o, OVFCAP); }
  __syncthreads();
  const u32* mypairs = pairs + (size_t)b*PCAP;
  for(int i=tid; i<cl; i+=512){
    u32 u = mypairs[i];
    atomicAdd(&dcnt[(u>>17)&63], 1);
  }
  __syncthreads();
  if(tid==0){
    int run=0;
    #pragma unroll
    for(int j=0;j<64;j++){ dstart[j]=run; dcur[j]=run; run+=dcnt[j]; }
    dstart[64]=run;
  }
  __syncthreads();
  for(int i=tid; i<cl; i+=512){
    u32 u = mypairs[i];
    int pos = atomicAdd(&dcur[(u>>17)&63], 1);
    lsrc[pos] = (int)(u & 0x1FFFFu);
  }
  __syncthreads();
  int ovfn = s_ovfn;
  const uint4* xr = (const uint4*)xb;
  int slot = tid >> 4;
  int c = tid & 15;
  for(int pass=0; pass<2; pass++){
    int r = pass*32 + slot;
    int node = b*64 + r;
    if(node >= N) continue;
    uint4 xv = xr[(size_t)node*16 + c];
    float acc[8] = {
      bf2f_lo(xv.x), bf2f_hi(xv.x), bf2f_lo(xv.y), bf2f_hi(xv.y),
      bf2f_lo(xv.z), bf2f_hi(xv.z), bf2f_lo(xv.w), bf2f_hi(xv.w) };
    int ds = dstart[r], de = dstart[r+1];
    int j = ds;
    for(; j+8 <= de; j += 8){
      int s0=lsrc[j+0], s1=lsrc[j+1], s2=lsrc[j+2], s3=lsrc[j+3];
      int s4=lsrc[j+4], s5=lsrc[j+5], s6=lsrc[j+6], s7=lsrc[j+7];
      uint4 v0 = xr[(size_t)s0*16 + c];
      uint4 v1 = xr[(size_t)s1*16 + c];
      uint4 v2 = xr[(size_t)s2*16 + c];
      uint4 v3 = xr[(size_t)s3*16 + c];
      uint4 v4 = xr[(size_t)s4*16 + c];
      uint4 v5 = xr[(size_t)s5*16 + c];
      uint4 v6 = xr[(size_t)s6*16 + c];
      uint4 v7 = xr[(size_t)s7*16 + c];
      acc[0]+=bf2f_lo(v0.x)+bf2f_lo(v1.x)+bf2f_lo(v2.x)+bf2f_lo(v3.x)
             +bf2f_lo(v4.x)+bf2f_lo(v5.x)+bf2f_lo(v6.x)+bf2f_lo(v7.x);
      acc[1]+=bf2f_hi(v0.x)+bf2f_hi(v1.x)+bf2f_hi(v2.x)+bf2f_hi(v3.x)
             +bf2f_hi(v4.x)+bf2f_hi(v5.x)+bf2f_hi(v6.x)+bf2f_hi(v7.x);
      acc[2]+=bf2f_lo(v0.y)+bf2f_lo(v1.y)+bf2f_lo(v2.y)+bf2f_lo(v3.y)
             +bf2f_lo(v4.y)+bf2f_lo(v5.y)+bf2f_lo(v6.y)+bf2f_lo(v7.y);
      acc[3]+=bf2f_hi(v0.y)+bf2f_hi(v1.y)+bf2f_hi(v2.y)+bf2f_hi(v3.y)
             +bf2f_hi(v4.y)+bf2f_hi(v5.y)+bf2f_hi(v6.y)+bf2f_hi(v7.y);
      acc[4]+=bf2f_lo(v0.z)+bf2f_lo(v1.z)+bf2f_lo(v2.z)+bf2f_lo(v3.z)
             +bf2f_lo(v4.z)+bf2f_lo(v5.z)+bf2f_lo(v6.z)+bf2f_lo(v7.z);
      acc[5]+=bf2f_hi(v0.z)+bf2f_hi(v1.z)+bf2f_hi(v2.z)+bf2f_hi(v3.z)
             +bf2f_hi(v4.z)+bf2f_hi(v5.z)+bf2f_hi(v6.z)+bf2f_hi(v7.z);
      acc[6]+=bf2f_lo(v0.w)+bf2f_lo(v1.w)+bf2f_lo(v2.w)+bf2f_lo(v3.w)
             +bf2f_lo(v4.w)+bf2f_lo(v5.w)+bf2f_lo(v6.w)+bf2f_lo(v7.w);
      acc[7]+=bf2f_hi(v0.w)+bf2f_hi(v1.w)+bf2f_hi(v2.w)+bf2f_hi(v3.w)
             +bf2f_hi(v4.w)+bf2f_hi(v5.w)+bf2f_hi(v6.w)+bf2f_hi(v7.w);
    }
    for(; j < de; j++){
      int s = lsrc[j];
      uint4 v = xr[(size_t)s*16 + c];
      acc[0]+=bf2f_lo(v.x); acc[1]+=bf2f_hi(v.x);
      acc[2]+=bf2f_lo(v.y); acc[3]+=bf2f_hi(v.y);
      acc[4]+=bf2f_lo(v.z); acc[5]+=bf2f_hi(v.z);
      acc[6]+=bf2f_lo(v.w); acc[7]+=bf2f_hi(v.w);
    }
    if(ovfn > 0){
      for(int i=0;i<ovfn;i++){
        int s = ovf[2*i], d = ovf[2*i+1];
        if(d == node){
          if((u32)s >= (u32)N) s = 0;
          uint4 v = xr[(size_t)s*16 + c];
          acc[0]+=bf2f_lo(v.x); acc[1]+=bf2f_hi(v.x);
          acc[2]+=bf2f_lo(v.y); acc[3]+=bf2f_hi(v.y);
          acc[4]+=bf2f_lo(v.z); acc[5]+=bf2f_hi(v.z);
          acc[6]+=bf2f_lo(v.w); acc[7]+=bf2f_hi(v.w);
        }
      }
    }
    uint4 o;
    o.x = pack2bf(acc[0],acc[1]); o.y = pack2bf(acc[2],acc[3]);
    o.z = pack2bf(acc[4],acc[5]); o.w = pack2bf(acc[6],acc[7]);
    ((uint4*)h0b)[(size_t)node*16 + c] = o;
  }
}

// =============== MFMA bf16 GEMM + optional fused column stats ===============
template<int K, bool BNA, bool RELUOUT, bool GATE, bool ABF16, bool OUTBF16, bool STATS>
__global__ __launch_bounds__(512) void gemm_mfma(const void* __restrict__ Ap, const ushort_t* __restrict__ Wt,
                                                 const float* __restrict__ bias,
                                                 const float* __restrict__ scale, const float* __restrict__ shift,
                                                 void* __restrict__ Cp, int M,
                                                 const float* __restrict__ Wg, const float* __restrict__ bg,
                                                 float* __restrict__ gate,
                                                 float* __restrict__ psum, float* __restrict__ pq, int NS){
  __shared__ uint4 Al[8*129];
  __shared__ uint4 Bl[8*257];
  __shared__ float gacc[128];
  __shared__ float sstat[512];
  const int tid  = threadIdx.x;
  const int lane = tid & 63;
  const int wave = tid >> 6;
  const int lm   = lane & 15;
  const int q    = lane >> 4;
  const int mhalf= wave >> 2;
  const int nq   = wave & 3;
  const int m0   = blockIdx.x * 128;

  if(GATE && tid < 128) gacc[tid] = 0.f;
  if(STATS){ sstat[tid] = 0.f; }

  f32x4 acc[4][4];
  #pragma unroll
  for(int i=0;i<4;i++)
    #pragma unroll
    for(int j=0;j<4;j++) acc[i][j] = (f32x4){0.f,0.f,0.f,0.f};

  for(int k0=0; k0<K; k0+=64){
    #pragma unroll
    for(int i=0;i<2;i++){
      int idx = tid*2 + i;
      int m = idx >> 3, c = idx & 7;
      int grow = m0 + m;
      int kk = k0 + c*8;
      uint4 v = make_uint4(0,0,0,0);
      if(ABF16){
        if(grow < M) v = *(const uint4*)((const ushort_t*)Ap + (size_t)grow*K + kk);
        if(BNA){
          float f0=bf2f_lo(v.x), f1=bf2f_hi(v.x), f2=bf2f_lo(v.y), f3=bf2f_hi(v.y);
          float f4=bf2f_lo(v.z), f5=bf2f_hi(v.z), f6=bf2f_lo(v.w), f7=bf2f_hi(v.w);
          float4 s0 = *(const float4*)(scale+kk),  s1 = *(const float4*)(scale+kk+4);
          float4 t0 = *(const float4*)(shift+kk),  t1 = *(const float4*)(shift+kk+4);
          f0=fmaxf(fmaf(s0.x,f0,t0.x),0.f); f1=fmaxf(fmaf(s0.y,f1,t0.y),0.f);
          f2=fmaxf(fmaf(s0.z,f2,t0.z),0.f); f3=fmaxf(fmaf(s0.w,f3,t0.w),0.f);
          f4=fmaxf(fmaf(s1.x,f4,t1.x),0.f); f5=fmaxf(fmaf(s1.y,f5,t1.y),0.f);
          f6=fmaxf(fmaf(s1.z,f6,t1.z),0.f); f7=fmaxf(fmaf(s1.w,f7,t1.w),0.f);
          v.x = pack2bf(f0,f1); v.y = pack2bf(f2,f3);
          v.z = pack2bf(f4,f5); v.w = pack2bf(f6,f7);
        }
      } else {
        float4 u0 = make_float4(0,0,0,0), u1 = make_float4(0,0,0,0);
        if(grow < M){
          u0 = *(const float4*)((const float*)Ap + (size_t)grow*K + kk);
          u1 = *(const float4*)((const float*)Ap + (size_t)grow*K + kk + 4);
        }
        if(BNA){
          float4 s0 = *(const float4*)(scale+kk),  s1 = *(const float4*)(scale+kk+4);
          float4 t0 = *(const float4*)(shift+kk),  t1 = *(const float4*)(shift+kk+4);
          u0.x=fmaxf(fmaf(s0.x,u0.x,t0.x),0.f); u0.y=fmaxf(fmaf(s0.y,u0.y,t0.y),0.f);
          u0.z=fmaxf(fmaf(s0.z,u0.z,t0.z),0.f); u0.w=fmaxf(fmaf(s0.w,u0.w,t0.w),0.f);
          u1.x=fmaxf(fmaf(s1.x,u1.x,t1.x),0.f); u1.y=fmaxf(fmaf(s1.y,u1.y,t1.y),0.f);
          u1.z=fmaxf(fmaf(s1.z,u1.z,t1.z),0.f); u1.w=fmaxf(fmaf(s1.w,u1.w,t1.w),0.f);
        }
        v.x = pack2bf(u0.x,u0.y); v.y = pack2bf(u0.z,u0.w);
        v.z = pack2bf(u1.x,u1.y); v.w = pack2bf(u1.z,u1.w);
      }
      Al[c*129 + m] = v;
    }
    #pragma unroll
    for(int i=0;i<4;i++){
      int idx = tid*4 + i;
      int n = idx >> 3, c = idx & 7;
      Bl[c*257 + n] = *(const uint4*)(Wt + (size_t)n*K + k0 + c*8);
    }
    __syncthreads();
    #pragma unroll
    for(int ks=0; ks<2; ks++){
      int cc = ks*4 + q;
      bf16x8 af[4], bfr[4];
      #pragma unroll
      for(int mi=0; mi<4; mi++)
        af[mi] = *((const bf16x8*)&Al[cc*129 + mhalf*64 + mi*16 + lm]);
      #pragma unroll
      for(int ni=0; ni<4; ni++)
        bfr[ni] = *((const bf16x8*)&Bl[cc*257 + nq*64 + ni*16 + lm]);
      #pragma unroll
      for(int mi=0; mi<4; mi++)
        #pragma unroll
        for(int ni=0; ni<4; ni++)
          acc[mi][ni] = __builtin_amdgcn_mfma_f32_16x16x32_bf16(af[mi], bfr[ni], acc[mi][ni], 0, 0, 0);
    }
    __syncthreads();
  }

  float bb[4], wgv[4];
  float cs[4] = {0.f,0.f,0.f,0.f};
  float cq[4] = {0.f,0.f,0.f,0.f};
  #pragma unroll
  for(int ni=0; ni<4; ni++){
    int col = nq*64 + ni*16 + lm;
    bb[ni] = bias[col];
    if(GATE) wgv[ni] = Wg[col];
  }
  #pragma unroll
  for(int mi=0; mi<4; mi++){
    int rowloc0 = mhalf*64 + mi*16 + q*4;
    float gp[4] = {0.f,0.f,0.f,0.f};
    #pragma unroll
    for(int ni=0; ni<4; ni++){
      int col = nq*64 + ni*16 + lm;
      f32x4 o = acc[mi][ni];
      #pragma unroll
      for(int r=0; r<4; r++){
        float v = o[r] + bb[ni];
        if(RELUOUT) v = fmaxf(v, 0.f);
        int row = m0 + rowloc0 + r;
        if(row < M){
          if(OUTBF16) ((ushort_t*)Cp)[(size_t)row*256 + col] = f2bf1(v);
          else        ((float*)Cp)[(size_t)row*256 + col] = v;
          if(STATS){ cs[ni] += v; cq[ni] = fmaf(v, v, cq[ni]); }
        }
        if(GATE) gp[r] = fmaf(v, wgv[ni], gp[r]);
      }
    }
    if(GATE){
      // reduce over the 16 lm-lanes (lane bits 0-3) so only 1 atomic per (wave,row)
      #pragma unroll
      for(int r=0; r<4; r++){
        float gv = gp[r];
        #pragma unroll
        for(int d=1; d<16; d<<=1) gv += __shfl_xor(gv, d, 64);
        if(lm == 0 && m0 + rowloc0 + r < M) atomicAdd(&gacc[rowloc0 + r], gv);
      }
    }
  }
  if(STATS){
    __syncthreads();
    #pragma unroll
    for(int ni=0; ni<4; ni++){
      int col = nq*64 + ni*16 + lm;
      atomicAdd(&sstat[col], cs[ni]);
      atomicAdd(&sstat[256+col], cq[ni]);
    }
    __syncthreads();
    if(tid < 256){
      psum[(size_t)tid*NS + blockIdx.x] = sstat[tid];
      pq[(size_t)tid*NS + blockIdx.x]   = sstat[256+tid];
    }
  }
  if(GATE){
    __syncthreads();
    if(tid < 128){
      int row = m0 + tid;
      if(row < M) gate[row] = gacc[tid] + bg[0];
    }
  }
}

// =============== stats finalize (for BN1) ===============
__global__ __launch_bounds__(512) void stats_fin(const float* __restrict__ psum, const float* __restrict__ pq,
                                                 const float* __restrict__ gamma, const float* __restrict__ beta,
                                                 float* __restrict__ scale, float* __restrict__ shift,
                                                 int nblk, int NS, float invM){
  __shared__ float red[512];
  int t = threadIdx.x;
  const float* src = (t<256) ? (psum + (size_t)t*NS) : (pq + (size_t)(t-256)*NS);
  float s = 0.f;
  int i = 0;
  for(; i+4 <= nblk; i += 4){
    float4 v = *(const float4*)(src+i);
    s += v.x+v.y+v.z+v.w;
  }
  for(; i < nblk; i++) s += src[i];
  red[t]=s; __syncthreads();
  if(t<256){
    float mu  = red[t]*invM;
    float var = fmaxf(red[256+t]*invM - mu*mu, 0.f);
    float sc  = gamma[t] * rsqrtf(var + 1e-5f);
    scale[t]=sc; shift[t]=fmaf(-mu, sc, beta[t]);
  }
}

// =============== attentional pool: block(512)/graph; uint2 (4 cols)/thread, 8 row streams ===============
__global__ __launch_bounds__(512) void pool_k(const ushort_t* __restrict__ h2b, const float* __restrict__ gate,
                                              const int* __restrict__ batch, float* __restrict__ pooled, int N){
  int g = blockIdx.x;
  __shared__ int sb[2];
  __shared__ float red[8];
  __shared__ float s_m, s_inv;
  __shared__ float la[256];
  __shared__ float sa[8*256];
  int t = threadIdx.x;
  if(t < 2){
    int target = g + t;
    int lo=0, hi=N;
    while(lo<hi){ int mid=(lo+hi)>>1; if(batch[mid] < target) lo=mid+1; else hi=mid; }
    sb[t] = lo;
  }
  __syncthreads();
  int beg = sb[0], end = sb[1];
  float mx = -1e30f;
  for(int i=beg+t; i<end; i+=512) mx = fmaxf(mx, gate[i]);
  #pragma unroll
  for(int d=32; d>0; d>>=1) mx = fmaxf(mx, __shfl_down(mx, d, 64));
  if((t&63)==0) red[t>>6] = mx;
  __syncthreads();
  if(t==0){
    float m = red[0];
    #pragma unroll
    for(int w=1; w<8; w++) m = fmaxf(m, red[w]);
    s_m = m;
  }
  __syncthreads();
  float m = s_m;
  float s = 0.f;
  for(int i=beg+t; i<end; i+=512) s += expf(gate[i]-m);
  #pragma unroll
  for(int d=32; d>0; d>>=1) s += __shfl_down(s, d, 64);
  if((t&63)==0) red[t>>6] = s;
  __syncthreads();
  if(t==0){
    float tot = 0.f;
    #pragma unroll
    for(int w=0; w<8; w++) tot += red[w];
    s_inv = (tot > 0.f) ? 1.f/tot : 0.f;
  }
  __syncthreads();
  float inv = s_inv;
  const uint2* h2w2 = (const uint2*)h2b;
  int cp = t & 63;
  int rowgrp = t >> 6;
  float a0=0.f, a1=0.f, a2=0.f, a3=0.f;
  for(int ci=beg; ci<end; ci+=256){
    int chunk = min(256, end-ci);
    if(t < 256) la[t] = (t < chunk) ? expf(gate[ci+t]-m)*inv : 0.f;
    __syncthreads();
    for(int j=rowgrp; j<chunk; j+=8){
      uint2 h = h2w2[(size_t)(ci+j)*64 + cp];
      float w = la[j];
      a0 = fmaf(w, bf2f_lo(h.x), a0);
      a1 = fmaf(w, bf2f_hi(h.x), a1);
      a2 = fmaf(w, bf2f_lo(h.y), a2);
      a3 = fmaf(w, bf2f_hi(h.y), a3);
    }
    __syncthreads();
  }
  *(float4*)&sa[rowgrp*256 + cp*4] = make_float4(a0,a1,a2,a3);
  __syncthreads();
  if(t < 256){
    float r = sa[t] + sa[256+t] + sa[512+t] + sa[768+t]
            + sa[1024+t] + sa[1280+t] + sa[1536+t] + sa[1792+t];
    pooled[g*256 + t] = r;
  }
}

// =============== fused tail: pooled partials (64 blocks) + last-block BN2+head ===============
__global__ __launch_bounds__(256) void tail_k(const float* __restrict__ pooled,
                                              const float* __restrict__ g2, const float* __restrict__ be2,
                                              const float* __restrict__ Wh, const float* __restrict__ bh,
                                              float* __restrict__ psum2, float* __restrict__ pq2,
                                              int* __restrict__ done, float* __restrict__ out, int G){
  int b = blockIdx.x;           // 64 blocks, 8 rows each
  int t = threadIdx.x;
  __shared__ float ls[1024];
  __shared__ float lq[1024];
  __shared__ int s_old;
  // --- phase 1: partials for rows b*8 .. b*8+7 (parallel, proven col_stats2 shape) ---
  {
    int grp = t >> 6, lane = t & 63, c0 = lane*4;
    int r0 = b*8, r1 = min(r0+8, G);
    float4 s4 = make_float4(0.f,0.f,0.f,0.f);
    float4 q4 = make_float4(0.f,0.f,0.f,0.f);
    for(int r=r0+grp; r<r1; r+=4){
      float4 v = *(const float4*)(pooled + (size_t)r*256 + c0);
      s4.x+=v.x; s4.y+=v.y; s4.z+=v.z; s4.w+=v.w;
      q4.x=fmaf(v.x,v.x,q4.x); q4.y=fmaf(v.y,v.y,q4.y);
      q4.z=fmaf(v.z,v.z,q4.z); q4.w=fmaf(v.w,v.w,q4.w);
    }
    *(float4*)&ls[grp*256+c0] = s4;
    *(float4*)&lq[grp*256+c0] = q4;
    __syncthreads();
    if(t < 64){
      #pragma unroll
      for(int j=0;j<4;j++){
        int c = c0+j;
        float s = ls[c]+ls[256+c]+ls[512+c]+ls[768+c];
        float q = lq[c]+lq[256+c]+lq[512+c]+lq[768+c];
        psum2[(size_t)c*64 + b] = s;
        pq2[(size_t)c*64 + b]   = q;
      }
    }
  }
  __threadfence();
  if(t==0) s_old = atomicAdd(done, 1);
  __syncthreads();
  if(s_old != 63) return;
  __threadfence();   // acquire: make all blocks' partials visible
  // --- phase 2 (last block only): BN2 finalize + head ---
  __shared__ float ssc[256], ssh[256];
  {
    int c = t;
    const float* srcs = psum2 + (size_t)c*64;
    const float* srcq = pq2 + (size_t)c*64;
    float s=0.f, q=0.f;
    for(int i=0;i<64;i+=4){
      float4 v = *(const float4*)(srcs+i); s += v.x+v.y+v.z+v.w;
      float4 w = *(const float4*)(srcq+i); q += w.x+w.y+w.z+w.w;
    }
    float invG = 1.f/(float)G;
    float mu = s*invG;
    float var = fmaxf(q*invG - mu*mu, 0.f);
    float sc = g2[c]*rsqrtf(var + 1e-5f);
    ssc[c] = sc; ssh[c] = fmaf(-mu, sc, be2[c]);
  }
  __syncthreads();
  int wv = t >> 6, l = t & 63;
  for(int w=wv; w<G; w+=4){
    float4 v  = *(const float4*)(pooled + (size_t)w*256 + l*4);
    float vv0 = fmaf(ssc[l*4+0], v.x, ssh[l*4+0]);
    float vv1 = fmaf(ssc[l*4+1], v.y, ssh[l*4+1]);
    float vv2 = fmaf(ssc[l*4+2], v.z, ssh[l*4+2]);
    float vv3 = fmaf(ssc[l*4+3], v.w, ssh[l*4+3]);
    float4 w0 = *(const float4*)(Wh + (size_t)l*8);
    float4 w1 = *(const float4*)(Wh + (size_t)l*8 + 4);
    float a0 = vv0*w0.x + vv1*w0.z + vv2*w1.x + vv3*w1.z;
    float a1 = vv0*w0.y + vv1*w0.w + vv2*w1.y + vv3*w1.w;
    #pragma unroll
    for(int d=32; d>0; d>>=1){ a0 += __shfl_down(a0,d,64); a1 += __shfl_down(a1,d,64); }
    if(l==0){
      float z0 = a0 + bh[0];
      float z1 = a1 + bh[1];
      float mz = fmaxf(z0,z1);
      float lse = mz + logf(expf(z0-mz) + expf(z1-mz));
      out[w*2]   = z0 - lse;
      out[w*2+1] = z1 - lse;
    }
  }
}

extern "C" void kernel_launch(void* const* d_in, const int* in_sizes, int n_in,
                              void* d_out, int out_size, void* d_ws, size_t ws_size,
                              hipStream_t stream){
  const float* x   = (const float*)d_in[0];
  const int*   ei  = (const int*)d_in[1];
  const int*   bat = (const int*)d_in[2];
  const float* W1  = (const float*)d_in[3];
  const float* b1  = (const float*)d_in[4];
  const float* g1  = (const float*)d_in[5];
  const float* be1 = (const float*)d_in[6];
  const float* W2  = (const float*)d_in[7];
  const float* b2  = (const float*)d_in[8];
  const float* Wg  = (const float*)d_in[9];
  const float* bg  = (const float*)d_in[10];
  const float* g2  = (const float*)d_in[11];
  const float* be2 = (const float*)d_in[12];
  const float* Wh  = (const float*)d_in[13];
  const float* bh  = (const float*)d_in[14];

  const int N = in_sizes[0] / 128;   // 50000
  const int E = in_sizes[1] / 2;     // 1600000
  const int G = out_size / 2;        // 512
  const int NB = (N + 63) >> 6;      // 782
  const int gblocks = (N + 127)/128; // 391
  const int NS1 = (gblocks + 7) & ~7; // 392

  // ---- workspace layout ----
  char* ws = (char*)d_ws;
  u32*   h0b    = (u32*)ws;                          // 12,800,000 B
  u32*   xb     = (u32*)(ws + 12800000);             // 12,800,000 B
  u32*   pairs  = (u32*)(ws + 25600000);             // NB*PCAP*4
  int*   bcursor= (int*)(ws + 35210240);             //     65,536 B
  int*   ovf_cnt= (int*)(ws + 35275776);             //  256 B ([0]=ovf, [16]=done)
  int*   ovf    = (int*)(ws + 35276032);             // 12,800,000 B
  ushort_t* h2b = (ushort_t*)ws;                     // 25,600,000 B (phase2)
  u32*   h1b    = (u32*)(ws + 51200000);             // 25,600,000 B
  char*  p2 = ws + 102400000;
  float* psum1 = (float*)p2;          p2 += 256*NS1*4;
  float* pq1   = (float*)p2;          p2 += 256*NS1*4;
  float* psum2 = (float*)p2;          p2 += 256*64*4;
  float* pq2   = (float*)p2;          p2 += 256*64*4;
  float* sc1   = (float*)p2;          p2 += 1024;
  float* sh1   = (float*)p2;          p2 += 1024;
  float* gate  = (float*)p2;          p2 += (size_t)N*4 + 4096;
  float* pooled= (float*)p2;          p2 += (size_t)G*256*4;
  ushort_t* W1t = (ushort_t*)p2;      p2 += 256*128*2;
  ushort_t* W2t = (ushort_t*)p2;      p2 += 256*256*2;

  const int* src = ei;
  const int* dst = ei + E;

  long nconv = (long)N*128/4/256;
  prep<<<(int)(nconv + 512 + 1), 256, 0, stream>>>(x, xb, nconv, W1, W1t, W2, W2t, bcursor, ovf_cnt, NB);

  int nchunk = (E + 4095)/4096;
  binscatter_direct<<<nchunk, 256, 0, stream>>>(src, dst, bcursor, pairs, ovf, ovf_cnt, E, N, NB);
  gather_bucket<<<NB, 512, 0, stream>>>(xb, pairs, bcursor, ovf, ovf_cnt, h0b, N);

  gemm_mfma<128,false,false,false,true,true,true><<<gblocks, 512, 0, stream>>>(
      h0b, W1t, b1, nullptr, nullptr, h1b, N, nullptr, nullptr, nullptr, psum1, pq1, NS1);
  stats_fin<<<1, 512, 0, stream>>>(psum1, pq1, g1, be1, sc1, sh1, gblocks, NS1, 1.0f/(float)N);
  gemm_mfma<256,true,true,true,true,true,false><<<gblocks, 512, 0, stream>>>(
      h1b, W2t, b2, sc1, sh1, h2b, N, Wg, bg, gate, nullptr, nullptr, 0);

  pool_k<<<G, 512, 0, stream>>>(h2b, gate, bat, pooled, N);
  tail_k<<<64, 256, 0, stream>>>(pooled, g2, be2, Wh, bh, psum2, pq2, &ovf_cnt[16], (float*)d_out, G);
}

// Round 19
// 341.163 us; speedup vs baseline: 1.1856x; 1.1856x over previous
//
#include <hip/hip_runtime.h>

typedef unsigned int u32;
typedef unsigned short ushort_t;
typedef __attribute__((ext_vector_type(8))) short bf16x8;
typedef __attribute__((ext_vector_type(4))) float f32x4;

#define PCAP 3072          // per-bucket fixed capacity (mean 2046, sigma ~45)
#define OVFCAP 1600000     // overflow list capacity = E (unconditional correctness)

__device__ __forceinline__ float bf2f_lo(u32 u){
  union{u32 i; float f;} v; v.i = u<<16; return v.f;
}
__device__ __forceinline__ float bf2f_hi(u32 u){
  union{u32 i; float f;} v; v.i = u & 0xFFFF0000u; return v.f;
}
__device__ __forceinline__ u32 pack2bf(float a, float b){
  union{float f; u32 i;} va, vb; va.f=a; vb.f=b;
  u32 ra = (va.i + 0x7FFF + ((va.i>>16)&1)) >> 16;          // RNE
  u32 rb = (vb.i + 0x7FFF + ((vb.i>>16)&1)) & 0xFFFF0000u;
  return ra | rb;
}
__device__ __forceinline__ ushort_t f2bf1(float f){
  union{float f; u32 i;} v; v.f=f;
  u32 r = v.i + 0x7FFF + ((v.i>>16)&1);
  return (ushort_t)(r>>16);
}

// =============== prep: x->bf16, W1^T, W2^T, zero control bufs (one launch) ===============
__global__ __launch_bounds__(256) void prep(const float* __restrict__ x, u32* __restrict__ xb, long nconv,
                                            const float* __restrict__ W1, ushort_t* __restrict__ W1t,
                                            const float* __restrict__ W2, ushort_t* __restrict__ W2t,
                                            int* __restrict__ bcursor, int* __restrict__ ovf_cnt, int NB){
  long blk = blockIdx.x;
  int tid = threadIdx.x;
  if(blk < nconv){
    long i = blk*256 + tid;                 // one float4 -> one uint2
    float4 v = ((const float4*)x)[i];
    uint2 o; o.x = pack2bf(v.x, v.y); o.y = pack2bf(v.z, v.w);
    ((uint2*)xb)[i] = o;
  } else if(blk < nconv + 256){
    int n = (int)(blk - nconv);
    for(int k = tid; k < 128; k += 256) W1t[(size_t)n*128 + k] = f2bf1(W1[(size_t)k*256 + n]);
  } else if(blk < nconv + 512){
    int n = (int)(blk - nconv - 256);
    for(int k = tid; k < 256; k += 256) W2t[(size_t)n*256 + k] = f2bf1(W2[(size_t)k*256 + n]);
  } else {
    for(int i = tid; i < NB*16; i += 256) bcursor[i] = 0;
    if(tid == 0) *ovf_cnt = 0;
  }
}

// =============== direct binned scatter: LDS-aggregated reservation, fixed-capacity buckets ===============
__global__ __launch_bounds__(256) void binscatter_direct(const int* __restrict__ src, const int* __restrict__ dst,
                                                         int* __restrict__ bcursor, u32* __restrict__ pairs,
                                                         int* __restrict__ ovf, int* __restrict__ ovf_cnt,
                                                         int E, int N, int NB){
  __shared__ int hist[1024];
  __shared__ int base[1024];
  int e0 = blockIdx.x*4096;
  int e1 = min(e0+4096, E);
  for(int i=threadIdx.x; i<NB; i+=256) hist[i]=0;
  __syncthreads();
  for(int i=e0+threadIdx.x; i<e1; i+=256){
    int d = dst[i];
    if((u32)d >= (u32)N) d = 0;
    atomicAdd(&hist[d>>6], 1);
  }
  __syncthreads();
  for(int i=threadIdx.x; i<NB; i+=256){
    int c = hist[i];
    base[i] = c ? atomicAdd(&bcursor[i*16], c) : 0;
    hist[i] = 0;
  }
  __syncthreads();
  for(int i=e0+threadIdx.x; i<e1; i+=256){
    int d = dst[i]; if((u32)d >= (u32)N) d = 0;
    int s = src[i]; if((u32)s >= (u32)N) s = 0;
    int b = d>>6;
    int loc = atomicAdd(&hist[b], 1);
    int pos = base[b] + loc;
    if(pos < PCAP){
      pairs[(size_t)b*PCAP + pos] = (u32)s | (((u32)(d & 63))<<17);
    } else {
      int o = atomicAdd(ovf_cnt, 1);
      if(o < OVFCAP){ ovf[2*o] = s; ovf[2*o+1] = d; }
    }
  }
}

// =============== fused bucket-CSR + gather: one block(512) per 64-node bucket ===============
__global__ __launch_bounds__(512) void gather_bucket(const u32* __restrict__ xb,
                                                     const u32* __restrict__ pairs,
                                                     const int* __restrict__ bcursor,
                                                     const int* __restrict__ ovf, const int* __restrict__ ovf_cnt,
                                                     u32* __restrict__ h0b, int N){
  __shared__ int lsrc[PCAP];
  __shared__ int dcnt[64];
  __shared__ int dstart[65];
  __shared__ int dcur[64];
  __shared__ int s_ovfn;
  int b = blockIdx.x;
  int tid = threadIdx.x;
  int cnt = bcursor[b*16];
  if(cnt < 0) cnt = 0;
  int cl = min(cnt, PCAP);
  if(tid < 64) dcnt[tid] = 0;
  if(tid == 0){ int o = *ovf_cnt; s_ovfn = (o < 0) ? 0 : min(o, OVFCAP); }
  __syncthreads();
  const u32* mypairs = pairs + (size_t)b*PCAP;
  for(int i=tid; i<cl; i+=512){
    u32 u = mypairs[i];
    atomicAdd(&dcnt[(u>>17)&63], 1);
  }
  __syncthreads();
  if(tid==0){
    int run=0;
    #pragma unroll
    for(int j=0;j<64;j++){ dstart[j]=run; dcur[j]=run; run+=dcnt[j]; }
    dstart[64]=run;
  }
  __syncthreads();
  for(int i=tid; i<cl; i+=512){
    u32 u = mypairs[i];
    int pos = atomicAdd(&dcur[(u>>17)&63], 1);
    lsrc[pos] = (int)(u & 0x1FFFFu);
  }
  __syncthreads();
  int ovfn = s_ovfn;
  const uint4* xr = (const uint4*)xb;
  int slot = tid >> 4;   // 0..31
  int c = tid & 15;      // 16B chunk of 256B row
  for(int pass=0; pass<2; pass++){
    int r = pass*32 + slot;
    int node = b*64 + r;
    if(node >= N) continue;
    uint4 xv = xr[(size_t)node*16 + c];
    float acc[8] = {
      bf2f_lo(xv.x), bf2f_hi(xv.x), bf2f_lo(xv.y), bf2f_hi(xv.y),
      bf2f_lo(xv.z), bf2f_hi(xv.z), bf2f_lo(xv.w), bf2f_hi(xv.w) };
    int ds = dstart[r], de = dstart[r+1];
    int j = ds;
    for(; j+8 <= de; j += 8){
      int s0=lsrc[j+0], s1=lsrc[j+1], s2=lsrc[j+2], s3=lsrc[j+3];
      int s4=lsrc[j+4], s5=lsrc[j+5], s6=lsrc[j+6], s7=lsrc[j+7];
      uint4 v0 = xr[(size_t)s0*16 + c];
      uint4 v1 = xr[(size_t)s1*16 + c];
      uint4 v2 = xr[(size_t)s2*16 + c];
      uint4 v3 = xr[(size_t)s3*16 + c];
      uint4 v4 = xr[(size_t)s4*16 + c];
      uint4 v5 = xr[(size_t)s5*16 + c];
      uint4 v6 = xr[(size_t)s6*16 + c];
      uint4 v7 = xr[(size_t)s7*16 + c];
      acc[0]+=bf2f_lo(v0.x)+bf2f_lo(v1.x)+bf2f_lo(v2.x)+bf2f_lo(v3.x)
             +bf2f_lo(v4.x)+bf2f_lo(v5.x)+bf2f_lo(v6.x)+bf2f_lo(v7.x);
      acc[1]+=bf2f_hi(v0.x)+bf2f_hi(v1.x)+bf2f_hi(v2.x)+bf2f_hi(v3.x)
             +bf2f_hi(v4.x)+bf2f_hi(v5.x)+bf2f_hi(v6.x)+bf2f_hi(v7.x);
      acc[2]+=bf2f_lo(v0.y)+bf2f_lo(v1.y)+bf2f_lo(v2.y)+bf2f_lo(v3.y)
             +bf2f_lo(v4.y)+bf2f_lo(v5.y)+bf2f_lo(v6.y)+bf2f_lo(v7.y);
      acc[3]+=bf2f_hi(v0.y)+bf2f_hi(v1.y)+bf2f_hi(v2.y)+bf2f_hi(v3.y)
             +bf2f_hi(v4.y)+bf2f_hi(v5.y)+bf2f_hi(v6.y)+bf2f_hi(v7.y);
      acc[4]+=bf2f_lo(v0.z)+bf2f_lo(v1.z)+bf2f_lo(v2.z)+bf2f_lo(v3.z)
             +bf2f_lo(v4.z)+bf2f_lo(v5.z)+bf2f_lo(v6.z)+bf2f_lo(v7.z);
      acc[5]+=bf2f_hi(v0.z)+bf2f_hi(v1.z)+bf2f_hi(v2.z)+bf2f_hi(v3.z)
             +bf2f_hi(v4.z)+bf2f_hi(v5.z)+bf2f_hi(v6.z)+bf2f_hi(v7.z);
      acc[6]+=bf2f_lo(v0.w)+bf2f_lo(v1.w)+bf2f_lo(v2.w)+bf2f_lo(v3.w)
             +bf2f_lo(v4.w)+bf2f_lo(v5.w)+bf2f_lo(v6.w)+bf2f_lo(v7.w);
      acc[7]+=bf2f_hi(v0.w)+bf2f_hi(v1.w)+bf2f_hi(v2.w)+bf2f_hi(v3.w)
             +bf2f_hi(v4.w)+bf2f_hi(v5.w)+bf2f_hi(v6.w)+bf2f_hi(v7.w);
    }
    for(; j < de; j++){
      int s = lsrc[j];
      uint4 v = xr[(size_t)s*16 + c];
      acc[0]+=bf2f_lo(v.x); acc[1]+=bf2f_hi(v.x);
      acc[2]+=bf2f_lo(v.y); acc[3]+=bf2f_hi(v.y);
      acc[4]+=bf2f_lo(v.z); acc[5]+=bf2f_hi(v.z);
      acc[6]+=bf2f_lo(v.w); acc[7]+=bf2f_hi(v.w);
    }
    if(ovfn > 0){
      for(int i=0;i<ovfn;i++){
        int s = ovf[2*i], d = ovf[2*i+1];
        if(d == node){
          if((u32)s >= (u32)N) s = 0;
          uint4 v = xr[(size_t)s*16 + c];
          acc[0]+=bf2f_lo(v.x); acc[1]+=bf2f_hi(v.x);
          acc[2]+=bf2f_lo(v.y); acc[3]+=bf2f_hi(v.y);
          acc[4]+=bf2f_lo(v.z); acc[5]+=bf2f_hi(v.z);
          acc[6]+=bf2f_lo(v.w); acc[7]+=bf2f_hi(v.w);
        }
      }
    }
    uint4 o;
    o.x = pack2bf(acc[0],acc[1]); o.y = pack2bf(acc[2],acc[3]);
    o.z = pack2bf(acc[4],acc[5]); o.w = pack2bf(acc[6],acc[7]);
    ((uint4*)h0b)[(size_t)node*16 + c] = o;
  }
}

// =============== MFMA bf16 GEMM + optional fused column stats ===============
template<int K, bool BNA, bool RELUOUT, bool GATE, bool ABF16, bool OUTBF16, bool STATS>
__global__ __launch_bounds__(512) void gemm_mfma(const void* __restrict__ Ap, const ushort_t* __restrict__ Wt,
                                                 const float* __restrict__ bias,
                                                 const float* __restrict__ scale, const float* __restrict__ shift,
                                                 void* __restrict__ Cp, int M,
                                                 const float* __restrict__ Wg, const float* __restrict__ bg,
                                                 float* __restrict__ gate,
                                                 float* __restrict__ psum, float* __restrict__ pq, int NS){
  __shared__ uint4 Al[8*129];
  __shared__ uint4 Bl[8*257];
  __shared__ float gacc[128];
  __shared__ float sstat[512];
  const int tid  = threadIdx.x;
  const int lane = tid & 63;
  const int wave = tid >> 6;
  const int lm   = lane & 15;
  const int q    = lane >> 4;
  const int mhalf= wave >> 2;
  const int nq   = wave & 3;
  const int m0   = blockIdx.x * 128;

  if(GATE && tid < 128) gacc[tid] = 0.f;
  if(STATS){ sstat[tid] = 0.f; }

  f32x4 acc[4][4];
  #pragma unroll
  for(int i=0;i<4;i++)
    #pragma unroll
    for(int j=0;j<4;j++) acc[i][j] = (f32x4){0.f,0.f,0.f,0.f};

  for(int k0=0; k0<K; k0+=64){
    #pragma unroll
    for(int i=0;i<2;i++){
      int idx = tid*2 + i;
      int m = idx >> 3, c = idx & 7;
      int grow = m0 + m;
      int kk = k0 + c*8;
      uint4 v = make_uint4(0,0,0,0);
      if(ABF16){
        if(grow < M) v = *(const uint4*)((const ushort_t*)Ap + (size_t)grow*K + kk);
        if(BNA){
          float f0=bf2f_lo(v.x), f1=bf2f_hi(v.x), f2=bf2f_lo(v.y), f3=bf2f_hi(v.y);
          float f4=bf2f_lo(v.z), f5=bf2f_hi(v.z), f6=bf2f_lo(v.w), f7=bf2f_hi(v.w);
          float4 s0 = *(const float4*)(scale+kk),  s1 = *(const float4*)(scale+kk+4);
          float4 t0 = *(const float4*)(shift+kk),  t1 = *(const float4*)(shift+kk+4);
          f0=fmaxf(fmaf(s0.x,f0,t0.x),0.f); f1=fmaxf(fmaf(s0.y,f1,t0.y),0.f);
          f2=fmaxf(fmaf(s0.z,f2,t0.z),0.f); f3=fmaxf(fmaf(s0.w,f3,t0.w),0.f);
          f4=fmaxf(fmaf(s1.x,f4,t1.x),0.f); f5=fmaxf(fmaf(s1.y,f5,t1.y),0.f);
          f6=fmaxf(fmaf(s1.z,f6,t1.z),0.f); f7=fmaxf(fmaf(s1.w,f7,t1.w),0.f);
          v.x = pack2bf(f0,f1); v.y = pack2bf(f2,f3);
          v.z = pack2bf(f4,f5); v.w = pack2bf(f6,f7);
        }
      } else {
        float4 u0 = make_float4(0,0,0,0), u1 = make_float4(0,0,0,0);
        if(grow < M){
          u0 = *(const float4*)((const float*)Ap + (size_t)grow*K + kk);
          u1 = *(const float4*)((const float*)Ap + (size_t)grow*K + kk + 4);
        }
        if(BNA){
          float4 s0 = *(const float4*)(scale+kk),  s1 = *(const float4*)(scale+kk+4);
          float4 t0 = *(const float4*)(shift+kk),  t1 = *(const float4*)(shift+kk+4);
          u0.x=fmaxf(fmaf(s0.x,u0.x,t0.x),0.f); u0.y=fmaxf(fmaf(s0.y,u0.y,t0.y),0.f);
          u0.z=fmaxf(fmaf(s0.z,u0.z,t0.z),0.f); u0.w=fmaxf(fmaf(s0.w,u0.w,t0.w),0.f);
          u1.x=fmaxf(fmaf(s1.x,u1.x,t1.x),0.f); u1.y=fmaxf(fmaf(s1.y,u1.y,t1.y),0.f);
          u1.z=fmaxf(fmaf(s1.z,u1.z,t1.z),0.f); u1.w=fmaxf(fmaf(s1.w,u1.w,t1.w),0.f);
        }
        v.x = pack2bf(u0.x,u0.y); v.y = pack2bf(u0.z,u0.w);
        v.z = pack2bf(u1.x,u1.y); v.w = pack2bf(u1.z,u1.w);
      }
      Al[c*129 + m] = v;
    }
    #pragma unroll
    for(int i=0;i<4;i++){
      int idx = tid*4 + i;
      int n = idx >> 3, c = idx & 7;
      Bl[c*257 + n] = *(const uint4*)(Wt + (size_t)n*K + k0 + c*8);
    }
    __syncthreads();
    #pragma unroll
    for(int ks=0; ks<2; ks++){
      int cc = ks*4 + q;
      bf16x8 af[4], bfr[4];
      #pragma unroll
      for(int mi=0; mi<4; mi++)
        af[mi] = *((const bf16x8*)&Al[cc*129 + mhalf*64 + mi*16 + lm]);
      #pragma unroll
      for(int ni=0; ni<4; ni++)
        bfr[ni] = *((const bf16x8*)&Bl[cc*257 + nq*64 + ni*16 + lm]);
      #pragma unroll
      for(int mi=0; mi<4; mi++)
        #pragma unroll
        for(int ni=0; ni<4; ni++)
          acc[mi][ni] = __builtin_amdgcn_mfma_f32_16x16x32_bf16(af[mi], bfr[ni], acc[mi][ni], 0, 0, 0);
    }
    __syncthreads();
  }

  float bb[4], wgv[4];
  float cs[4] = {0.f,0.f,0.f,0.f};
  float cq[4] = {0.f,0.f,0.f,0.f};
  #pragma unroll
  for(int ni=0; ni<4; ni++){
    int col = nq*64 + ni*16 + lm;
    bb[ni] = bias[col];
    if(GATE) wgv[ni] = Wg[col];
  }
  #pragma unroll
  for(int mi=0; mi<4; mi++){
    int rowloc0 = mhalf*64 + mi*16 + q*4;
    float gp[4] = {0.f,0.f,0.f,0.f};
    #pragma unroll
    for(int ni=0; ni<4; ni++){
      int col = nq*64 + ni*16 + lm;
      f32x4 o = acc[mi][ni];
      #pragma unroll
      for(int r=0; r<4; r++){
        float v = o[r] + bb[ni];
        if(RELUOUT) v = fmaxf(v, 0.f);
        int row = m0 + rowloc0 + r;
        if(row < M){
          if(OUTBF16) ((ushort_t*)Cp)[(size_t)row*256 + col] = f2bf1(v);
          else        ((float*)Cp)[(size_t)row*256 + col] = v;
          if(STATS){ cs[ni] += v; cq[ni] = fmaf(v, v, cq[ni]); }
        }
        if(GATE) gp[r] = fmaf(v, wgv[ni], gp[r]);
      }
    }
    if(GATE){
      #pragma unroll
      for(int r=0; r<4; r++){
        if(m0 + rowloc0 + r < M) atomicAdd(&gacc[rowloc0 + r], gp[r]);
      }
    }
  }
  if(STATS){
    __syncthreads();
    #pragma unroll
    for(int ni=0; ni<4; ni++){
      int col = nq*64 + ni*16 + lm;
      atomicAdd(&sstat[col], cs[ni]);
      atomicAdd(&sstat[256+col], cq[ni]);
    }
    __syncthreads();
    if(tid < 256){
      psum[(size_t)tid*NS + blockIdx.x] = sstat[tid];
      pq[(size_t)tid*NS + blockIdx.x]   = sstat[256+tid];
    }
  }
  if(GATE){
    __syncthreads();
    if(tid < 128){
      int row = m0 + tid;
      if(row < M) gate[row] = gacc[tid] + bg[0];
    }
  }
}

// =============== fp32 col stats partials (for pooled) ===============
__global__ __launch_bounds__(256) void col_stats2(const float* __restrict__ h, float* __restrict__ psum,
                                                  float* __restrict__ pq, int M, int rpb, int nblk){
  int b = blockIdx.x;
  int g = threadIdx.x >> 6;
  int lane = threadIdx.x & 63;
  int c0 = lane*4;
  int r0 = b*rpb;
  int r1 = min(r0+rpb, M);
  float4 s4 = make_float4(0.f,0.f,0.f,0.f);
  float4 q4 = make_float4(0.f,0.f,0.f,0.f);
  for(int r=r0+g; r<r1; r+=4){
    float4 v = *(const float4*)(h + (size_t)r*256 + c0);
    s4.x+=v.x; s4.y+=v.y; s4.z+=v.z; s4.w+=v.w;
    q4.x=fmaf(v.x,v.x,q4.x); q4.y=fmaf(v.y,v.y,q4.y);
    q4.z=fmaf(v.z,v.z,q4.z); q4.w=fmaf(v.w,v.w,q4.w);
  }
  __shared__ float ls[1024];
  __shared__ float lq[1024];
  *(float4*)&ls[g*256+c0] = s4;
  *(float4*)&lq[g*256+c0] = q4;
  __syncthreads();
  if(threadIdx.x < 64){
    #pragma unroll
    for(int j=0;j<4;j++){
      int c = c0+j;
      float s = ls[c]+ls[256+c]+ls[512+c]+ls[768+c];
      float q = lq[c]+lq[256+c]+lq[512+c]+lq[768+c];
      psum[(size_t)c*nblk + b] = s;
      pq[(size_t)c*nblk + b]   = q;
    }
  }
}

// =============== stats finalize (exact bound, no memset needed) ===============
__global__ __launch_bounds__(512) void stats_fin(const float* __restrict__ psum, const float* __restrict__ pq,
                                                 const float* __restrict__ gamma, const float* __restrict__ beta,
                                                 float* __restrict__ scale, float* __restrict__ shift,
                                                 int nblk, int NS, float invM){
  __shared__ float red[512];
  int t = threadIdx.x;
  const float* src = (t<256) ? (psum + (size_t)t*NS) : (pq + (size_t)(t-256)*NS);
  float s = 0.f;
  int i = 0;
  for(; i+4 <= nblk; i += 4){
    float4 v = *(const float4*)(src+i);
    s += v.x+v.y+v.z+v.w;
  }
  for(; i < nblk; i++) s += src[i];
  red[t]=s; __syncthreads();
  if(t<256){
    float mu  = red[t]*invM;
    float var = fmaxf(red[256+t]*invM - mu*mu, 0.f);
    float sc  = gamma[t] * rsqrtf(var + 1e-5f);
    scale[t]=sc; shift[t]=fmaf(-mu, sc, beta[t]);
  }
}

// =============== attentional pool: block(512)/graph; uint2 (4 cols)/thread, 8 row streams ===============
__global__ __launch_bounds__(512) void pool_k(const ushort_t* __restrict__ h2b, const float* __restrict__ gate,
                                              const int* __restrict__ batch, float* __restrict__ pooled, int N){
  int g = blockIdx.x;
  __shared__ int sb[2];
  __shared__ float red[8];
  __shared__ float s_m, s_inv;
  __shared__ float la[256];
  __shared__ float sa[8*256];
  int t = threadIdx.x;
  if(t < 2){
    int target = g + t;
    int lo=0, hi=N;
    while(lo<hi){ int mid=(lo+hi)>>1; if(batch[mid] < target) lo=mid+1; else hi=mid; }
    sb[t] = lo;
  }
  __syncthreads();
  int beg = sb[0], end = sb[1];
  float mx = -1e30f;
  for(int i=beg+t; i<end; i+=512) mx = fmaxf(mx, gate[i]);
  #pragma unroll
  for(int d=32; d>0; d>>=1) mx = fmaxf(mx, __shfl_down(mx, d, 64));
  if((t&63)==0) red[t>>6] = mx;
  __syncthreads();
  if(t==0){
    float m = red[0];
    #pragma unroll
    for(int w=1; w<8; w++) m = fmaxf(m, red[w]);
    s_m = m;
  }
  __syncthreads();
  float m = s_m;
  float s = 0.f;
  for(int i=beg+t; i<end; i+=512) s += expf(gate[i]-m);
  #pragma unroll
  for(int d=32; d>0; d>>=1) s += __shfl_down(s, d, 64);
  if((t&63)==0) red[t>>6] = s;
  __syncthreads();
  if(t==0){
    float tot = 0.f;
    #pragma unroll
    for(int w=0; w<8; w++) tot += red[w];
    s_inv = (tot > 0.f) ? 1.f/tot : 0.f;
  }
  __syncthreads();
  float inv = s_inv;
  const uint2* h2w2 = (const uint2*)h2b;   // uint2 = 4 bf16 cols; row = 64 uint2
  int cp = t & 63;       // uint2 index -> cols cp*4..cp*4+3
  int rowgrp = t >> 6;   // 0..7
  float a0=0.f, a1=0.f, a2=0.f, a3=0.f;
  for(int ci=beg; ci<end; ci+=256){
    int chunk = min(256, end-ci);
    if(t < 256) la[t] = (t < chunk) ? expf(gate[ci+t]-m)*inv : 0.f;
    __syncthreads();
    for(int j=rowgrp; j<chunk; j+=8){
      uint2 h = h2w2[(size_t)(ci+j)*64 + cp];
      float w = la[j];
      a0 = fmaf(w, bf2f_lo(h.x), a0);
      a1 = fmaf(w, bf2f_hi(h.x), a1);
      a2 = fmaf(w, bf2f_lo(h.y), a2);
      a3 = fmaf(w, bf2f_hi(h.y), a3);
    }
    __syncthreads();
  }
  *(float4*)&sa[rowgrp*256 + cp*4] = make_float4(a0,a1,a2,a3);
  __syncthreads();
  if(t < 256){
    float r = sa[t] + sa[256+t] + sa[512+t] + sa[768+t]
            + sa[1024+t] + sa[1280+t] + sa[1536+t] + sa[1792+t];
    pooled[g*256 + t] = r;
  }
}

// =============== head linear + log_softmax: one wave per graph ===============
__global__ __launch_bounds__(256) void head_k(const float* __restrict__ pooled,
                                              const float* __restrict__ sc2, const float* __restrict__ sh2,
                                              const float* __restrict__ Wh, const float* __restrict__ bh,
                                              float* __restrict__ out, int G){
  int w = (blockIdx.x*256 + threadIdx.x) >> 6;
  int l = threadIdx.x & 63;
  if(w >= G) return;
  float4 v  = *(const float4*)(pooled + (size_t)w*256 + l*4);
  float4 sc = *(const float4*)(sc2 + l*4);
  float4 sh = *(const float4*)(sh2 + l*4);
  float vv[4] = { fmaf(sc.x,v.x,sh.x), fmaf(sc.y,v.y,sh.y), fmaf(sc.z,v.z,sh.z), fmaf(sc.w,v.w,sh.w) };
  float4 w0 = *(const float4*)(Wh + (size_t)l*8);
  float4 w1 = *(const float4*)(Wh + (size_t)l*8 + 4);
  float a0 = vv[0]*w0.x + vv[1]*w0.z + vv[2]*w1.x + vv[3]*w1.z;
  float a1 = vv[0]*w0.y + vv[1]*w0.w + vv[2]*w1.y + vv[3]*w1.w;
  #pragma unroll
  for(int d=32; d>0; d>>=1){ a0 += __shfl_down(a0,d,64); a1 += __shfl_down(a1,d,64); }
  if(l==0){
    float z0 = a0 + bh[0];
    float z1 = a1 + bh[1];
    float mz = fmaxf(z0,z1);
    float lse = mz + logf(expf(z0-mz) + expf(z1-mz));
    out[w*2]   = z0 - lse;
    out[w*2+1] = z1 - lse;
  }
}

extern "C" void kernel_launch(void* const* d_in, const int* in_sizes, int n_in,
                              void* d_out, int out_size, void* d_ws, size_t ws_size,
                              hipStream_t stream){
  const float* x   = (const float*)d_in[0];
  const int*   ei  = (const int*)d_in[1];
  const int*   bat = (const int*)d_in[2];
  const float* W1  = (const float*)d_in[3];
  const float* b1  = (const float*)d_in[4];
  const float* g1  = (const float*)d_in[5];
  const float* be1 = (const float*)d_in[6];
  const float* W2  = (const float*)d_in[7];
  const float* b2  = (const float*)d_in[8];
  const float* Wg  = (const float*)d_in[9];
  const float* bg  = (const float*)d_in[10];
  const float* g2  = (const float*)d_in[11];
  const float* be2 = (const float*)d_in[12];
  const float* Wh  = (const float*)d_in[13];
  const float* bh  = (const float*)d_in[14];

  const int N = in_sizes[0] / 128;   // 50000
  const int E = in_sizes[1] / 2;     // 1600000
  const int G = out_size / 2;        // 512
  const int NB = (N + 63) >> 6;      // 782
  const int gblocks = (N + 127)/128; // 391
  const int NS1 = (gblocks + 7) & ~7; // 392
  const int NBLK2 = 64;

  // ---- workspace layout ----
  char* ws = (char*)d_ws;
  u32*   h0b    = (u32*)ws;                          // 12,800,000 B
  u32*   xb     = (u32*)(ws + 12800000);             // 12,800,000 B
  u32*   pairs  = (u32*)(ws + 25600000);             // NB*PCAP*4 = 9,609,216 B
  int*   bcursor= (int*)(ws + 35210240);             //     65,536 B
  int*   ovf_cnt= (int*)(ws + 35275776);             //        256 B
  int*   ovf    = (int*)(ws + 35276032);             // 2*E*4 = 12,800,000 B
  ushort_t* h2b = (ushort_t*)ws;                     // 25,600,000 B (phase2, overlays h0b+xb)
  u32*   h1b    = (u32*)(ws + 51200000);             // 25,600,000 B (bf16 pairs)
  char*  p2 = ws + 102400000;
  float* psum1 = (float*)p2;          p2 += 256*NS1*4;
  float* pq1   = (float*)p2;          p2 += 256*NS1*4;
  float* psum2 = (float*)p2;          p2 += 256*NBLK2*4;
  float* pq2   = (float*)p2;          p2 += 256*NBLK2*4;
  float* sc1   = (float*)p2;          p2 += 1024;
  float* sh1   = (float*)p2;          p2 += 1024;
  float* sc2   = (float*)p2;          p2 += 1024;
  float* sh2   = (float*)p2;          p2 += 1024;
  float* gate  = (float*)p2;          p2 += (size_t)N*4 + 4096;
  float* pooled= (float*)p2;          p2 += (size_t)G*256*4;
  ushort_t* W1t = (ushort_t*)p2;      p2 += 256*128*2;
  ushort_t* W2t = (ushort_t*)p2;      p2 += 256*256*2;

  const int* src = ei;
  const int* dst = ei + E;

  long nconv = (long)N*128/4/256;    // 6250 blocks for x conversion
  prep<<<(int)(nconv + 512 + 1), 256, 0, stream>>>(x, xb, nconv, W1, W1t, W2, W2t, bcursor, ovf_cnt, NB);

  int nchunk = (E + 4095)/4096;
  binscatter_direct<<<nchunk, 256, 0, stream>>>(src, dst, bcursor, pairs, ovf, ovf_cnt, E, N, NB);
  gather_bucket<<<NB, 512, 0, stream>>>(xb, pairs, bcursor, ovf, ovf_cnt, h0b, N);

  gemm_mfma<128,false,false,false,true,true,true><<<gblocks, 512, 0, stream>>>(
      h0b, W1t, b1, nullptr, nullptr, h1b, N, nullptr, nullptr, nullptr, psum1, pq1, NS1);
  stats_fin<<<1, 512, 0, stream>>>(psum1, pq1, g1, be1, sc1, sh1, gblocks, NS1, 1.0f/(float)N);
  gemm_mfma<256,true,true,true,true,true,false><<<gblocks, 512, 0, stream>>>(
      h1b, W2t, b2, sc1, sh1, h2b, N, Wg, bg, gate, nullptr, nullptr, 0);

  pool_k<<<G, 512, 0, stream>>>(h2b, gate, bat, pooled, N);
  int rpb2 = (G + NBLK2 - 1)/NBLK2;
  col_stats2<<<NBLK2, 256, 0, stream>>>(pooled, psum2, pq2, G, rpb2, NBLK2);
  stats_fin<<<1, 512, 0, stream>>>(psum2, pq2, g2, be2, sc2, sh2, NBLK2, NBLK2, 1.0f/(float)G);
  head_k<<<(G+3)/4, 256, 0, stream>>>(pooled, sc2, sh2, Wh, bh, (float*)d_out, G);
}